// Round 8
// baseline (113.335 us; speedup 1.0000x reference)
//
#include <hip/hip_runtime.h>
#include <math.h>

#define N 1024
#define C 81
#define F 1024
#define K 100
#define NC1 80              // C-1 foreground classes
#define MAXC (NC1 * N)      // dense candidate capacity
#define HBASE 0x3D00        // hist bucket base: float bits >>16
#define HSIZE 1024          // covers score in (0.05, 1]: buckets 76..640
#define SELCAP 2048         // select capacity (overlays sbox: 2048*8=16KB)

#define SCORE_THRESH 0.05f
#define NMS_THRESH   0.5f
#define BBOX_CLIP    4.135166556742356f   // log(1000/16)
#define IMG_W1       1215.0f
#define IMG_H1       799.0f

typedef unsigned long long u64;
typedef unsigned int u32;

// ---- decode one (proposal idx, class cl) box — expressions verbatim from the
// absmax==0 kernels so contraction/codegen matches.
__device__ float4 decode_box(const float* __restrict__ pboxes,
                             const float* __restrict__ boxreg, int idx, int cl)
{
    float4 pb = ((const float4*)pboxes)[idx];
    float4 r  = *(const float4*)(boxreg + (size_t)idx * (C * 4) + cl * 4);
    float w  = pb.z - pb.x + 1.0f, h = pb.w - pb.y + 1.0f;
    float cx = pb.x + 0.5f * w,  cy = pb.y + 0.5f * h;
    float dx = r.x / 10.0f, dy = r.y / 10.0f;
    float dw = fminf(r.z / 5.0f, BBOX_CLIP);
    float dh = fminf(r.w / 5.0f, BBOX_CLIP);
    float pcx = dx * w + cx, pcy = dy * h + cy;
    float pw = expf(dw) * w, ph = expf(dh) * h;
    float x1 = pcx - 0.5f * pw,        y1 = pcy - 0.5f * ph;
    float x2 = pcx + 0.5f * pw - 1.0f, y2 = pcy + 0.5f * ph - 1.0f;
    x1 = fminf(fmaxf(x1, 0.0f), IMG_W1);
    y1 = fminf(fmaxf(y1, 0.0f), IMG_H1);
    x2 = fminf(fmaxf(x2, 0.0f), IMG_W1);
    y2 = fminf(fmaxf(y2, 0.0f), IMG_H1);
    return make_float4(x1, y1, x2, y2);
}

// ---------------- per-row softmax stats (m, s), computed ONCE ---------------
// one wave per row, bit-exact replica of the original butterfly. Also zeroes
// hist + counter + done (grid covers HSIZE threads). ms[r] = (max, denom).
__global__ __launch_bounds__(256) void k_softmax(
    const float* __restrict__ logits, float2* __restrict__ ms,
    int* __restrict__ hist, int* __restrict__ counter, int* __restrict__ done)
{
    int gid = blockIdx.x * 256 + threadIdx.x;
    if (gid < HSIZE) hist[gid] = 0;
    if (gid == 0) { *counter = 0; *done = 0; }

    int n = blockIdx.x * 4 + (threadIdx.x >> 6);
    int t = threadIdx.x & 63;

    float v1 = logits[n * C + t];
    float v2 = (t < C - 64) ? logits[n * C + 64 + t] : -INFINITY;
    float m = fmaxf(v1, v2);
    for (int off = 32; off; off >>= 1) m = fmaxf(m, __shfl_xor(m, off));
    float e1 = expf(v1 - m);
    float e2 = (t < C - 64) ? expf(v2 - m) : 0.0f;
    float s = e1 + e2;
    for (int off = 32; off; off >>= 1) s += __shfl_xor(s, off);

    if (t == 0) ms[n] = make_float2(m, s);
}

// ---------------- mega: per-class NMS + last-block select + gather ----------
// 80 blocks. Class phase = round-6/7 proven logic (ballot compaction, wave
// path V<=64, bitmask NMS V<=256), with the V<=256 sort upgraded to the
// round-7-proven register bitonic. Last-arriving block (threadfence +
// atomicAdd(done) — round-5-proven discipline) runs select (round-4/5 proven
// two-level arithmetic + round-7 wave suffix scan + register bitonic) and the
// gather inline, sel results held in LDS.
__global__ __launch_bounds__(256) void k_mega(
    const float* __restrict__ logits, const float* __restrict__ boxreg,
    const float* __restrict__ pboxes, const float2* __restrict__ ms,
    const float* __restrict__ feats,
    u64* __restrict__ ckey, float4* __restrict__ cbox, int* __restrict__ corig,
    int* __restrict__ hist, int* __restrict__ counter, int* __restrict__ done,
    float* __restrict__ out)
{
    int c = blockIdx.x;            // foreground class (label = c+1)
    int cl = c + 1;
    int t = threadIdx.x;
    int lane = t & 63, wv = t >> 6;

    __shared__ u64    skey64[N];
    __shared__ float4 sbox[N];         // select phase overlays keys[] here
    __shared__ float  sarea[N];
    __shared__ int    skeep[N];
    __shared__ u64    sup[256][4];     // suppression matrix for V<=256
    __shared__ u64    skw[4];          // final keep words
    __shared__ int    swc[4];          // per-wave candidate counts
    __shared__ int    sLast;
    // select/gather phase:
    __shared__ int    swsum4[4];
    __shared__ int    sbstar, scount;
    __shared__ u64    wk[4];
    __shared__ int    wp[4];
    __shared__ float  ssel_score[K];
    __shared__ int    ssel_flat[K];
    __shared__ int    sorig[K];
    __shared__ int    sok[K];

    // ============ class phase: score -> threshold -> sort -> NMS ===========
    float2 p0 = ms[t],       p1 = ms[t + 256];
    float2 p2 = ms[t + 512], p3 = ms[t + 768];
    float s0 = expf(logits[(t      ) * C + cl] - p0.x) / p0.y;
    float s1 = expf(logits[(t + 256) * C + cl] - p1.x) / p1.y;
    float s2 = expf(logits[(t + 512) * C + cl] - p2.x) / p2.y;
    float s3 = expf(logits[(t + 768) * C + cl] - p3.x) / p3.y;
    int f0 = s0 > SCORE_THRESH, f1 = s1 > SCORE_THRESH;
    int f2 = s2 > SCORE_THRESH, f3 = s3 > SCORE_THRESH;

    // ---- ballot compaction (proven round 6) ----
    u64 lmask = (1ull << lane) - 1ull;
    u64 b0 = __ballot(f0), b1 = __ballot(f1);
    u64 b2 = __ballot(f2), b3 = __ballot(f3);
    int wcount = __popcll(b0) + __popcll(b1) + __popcll(b2) + __popcll(b3);
    if (lane == 0) swc[wv] = wcount;
    __syncthreads();
    int w0c = swc[0], w1c = swc[1], w2c = swc[2], w3c = swc[3];
    int V = w0c + w1c + w2c + w3c;
    int wbase = (wv > 0 ? w0c : 0) + (wv > 1 ? w1c : 0) + (wv > 2 ? w2c : 0);
    {
        int o0 = wbase;
        int o1 = o0 + __popcll(b0);
        int o2 = o1 + __popcll(b1);
        int o3 = o2 + __popcll(b2);
        if (f0) skey64[o0 + __popcll(b0 & lmask)] =
            ((u64)__float_as_uint(s0) << 32) | (u32)~(u32)(t);
        if (f1) skey64[o1 + __popcll(b1 & lmask)] =
            ((u64)__float_as_uint(s1) << 32) | (u32)~(u32)(t + 256);
        if (f2) skey64[o2 + __popcll(b2 & lmask)] =
            ((u64)__float_as_uint(s2) << 32) | (u32)~(u32)(t + 512);
        if (f3) skey64[o3 + __popcll(b3 & lmask)] =
            ((u64)__float_as_uint(s3) << 32) | (u32)~(u32)(t + 768);
    }
    __syncthreads();

    if (V > 0 && V <= 64) {
        // ---------- proven wave path ----------
        if (t < 64) {
            u64 key = (lane < V) ? skey64[lane] : 0ull;
            for (int k = 2; k <= 64; k <<= 1) {
                for (int j = k >> 1; j > 0; j >>= 1) {
                    u64 other = __shfl_xor(key, j);
                    bool takeMax = (((lane & j) == 0) == ((lane & k) == 0));
                    bool gt = key > other;
                    key = (takeMax == gt) ? key : other;
                }
            }
            bool act = key != 0ull;
            float4 b = make_float4(0.f, 0.f, 0.f, 0.f);
            float area = 0.0f;
            if (act) {
                int idx = (int)(~(u32)(key & 0xffffffffu));
                b = decode_box(pboxes, boxreg, idx, cl);
                area = (b.z - b.x + 1.0f) * (b.w - b.y + 1.0f);
                cbox[c * N + lane]  = b;
                corig[c * N + lane] = idx;
            }
            int kept = act ? 1 : 0;
            for (int i = 0; i + 1 < V; ++i) {
                int   ki  = __shfl(kept, i);
                float bix = __shfl(b.x, i), biy = __shfl(b.y, i);
                float biz = __shfl(b.z, i), biw = __shfl(b.w, i);
                float ai  = __shfl(area, i);
                if (ki && lane > i && kept) {
                    float lx = fmaxf(bix, b.x), ly = fmaxf(biy, b.y);
                    float rx = fminf(biz, b.z), ry = fminf(biw, b.w);
                    float ww = fmaxf(rx - lx + 1.0f, 0.0f);
                    float hh = fmaxf(ry - ly + 1.0f, 0.0f);
                    float inter = ww * hh;
                    float iou = inter / (ai + area - inter);
                    if (iou > NMS_THRESH) kept = 0;
                }
            }
            if (kept) {
                int pos = atomicAdd(counter, 1);
                u32 sb = (u32)(key >> 32);
                ckey[pos] = ((u64)sb << 32) | (u64)(u32)~(u32)(c * N + lane);
                atomicAdd(&hist[(int)(sb >> 16) - HBASE], 1);
            }
        }
    } else if (V > 64 && V <= 256) {
        // ---------- register bitonic (round-7-proven formula) ----------
        int P = 128;
        while (P < V) P <<= 1;
        u64 key = (t < V) ? skey64[t] : 0ull;
        for (int k = 2; k <= P; k <<= 1) {
            for (int j = k >> 1; j > 0; j >>= 1) {
                if (j >= 64) {
                    if (t < P) skey64[t] = key;
                    __syncthreads();
                    if (t < P) {
                        u64 other = skey64[t ^ j];
                        bool takeMax = (((t & j) == 0) == ((t & k) == 0));
                        bool gt = key > other;
                        key = (takeMax == gt) ? key : other;
                    }
                    __syncthreads();
                } else {
                    u64 other = __shfl_xor(key, j);
                    bool takeMax = (((t & j) == 0) == ((t & k) == 0));
                    bool gt = key > other;
                    if (t < P) key = (takeMax == gt) ? key : other;
                }
            }
        }
        if (t < P) skey64[t] = key;
        __syncthreads();
        // decode sorted candidates
        if (t < V) {
            int idx = (int)(~(u32)(skey64[t] & 0xffffffffu));
            float4 b = decode_box(pboxes, boxreg, idx, cl);
            sbox[t]  = b;
            sarea[t] = (b.z - b.x + 1.0f) * (b.w - b.y + 1.0f);
            cbox[c * N + t]  = b;
            corig[c * N + t] = idx;
        }
        __syncthreads();
        // parallel suppression matrix (proven round 6)
        if (t < V) {
            int i = t;
            float4 bi = sbox[i];
            float  ai = sarea[i];
            u64 w[4] = {0ull, 0ull, 0ull, 0ull};
            #pragma unroll
            for (int g = 0; g < 4; ++g) {
                int jlo = (i + 1 > g * 64) ? i + 1 : g * 64;
                int jhi = (V < (g + 1) * 64) ? V : (g + 1) * 64;
                for (int j = jlo; j < jhi; ++j) {
                    float4 bj = sbox[j];
                    float lx = fmaxf(bi.x, bj.x), ly = fmaxf(bi.y, bj.y);
                    float rx = fminf(bi.z, bj.z), ry = fminf(bi.w, bj.w);
                    float ww = fmaxf(rx - lx + 1.0f, 0.0f);
                    float hh = fmaxf(ry - ly + 1.0f, 0.0f);
                    float inter = ww * hh;
                    float iou = inter / (ai + sarea[j] - inter);
                    if (iou > NMS_THRESH) w[g] |= 1ull << (j & 63);
                }
            }
            sup[i][0] = w[0]; sup[i][1] = w[1];
            sup[i][2] = w[2]; sup[i][3] = w[3];
        }
        __syncthreads();
        // barrier-free walk on wave 0 (proven round 6)
        if (t < 64) {
            u64 r0w0 = sup[t][0], r0w1 = sup[t][1], r0w2 = sup[t][2], r0w3 = sup[t][3];
            u64 r1w1 = 0, r1w2 = 0, r1w3 = 0;
            u64 r2w2 = 0, r2w3 = 0;
            u64 r3w3 = 0;
            if (64 + t < V)  { r1w1 = sup[64 + t][1];  r1w2 = sup[64 + t][2];  r1w3 = sup[64 + t][3]; }
            if (128 + t < V) { r2w2 = sup[128 + t][2]; r2w3 = sup[128 + t][3]; }
            if (192 + t < V) { r3w3 = sup[192 + t][3]; }
            u64 k0 = ~0ull, k1 = ~0ull, k2 = ~0ull, k3 = ~0ull;
            {
                int lim = (V < 64) ? V : 64;
                for (int i = 0; i < lim; ++i)
                    if ((k0 >> i) & 1) {
                        k0 &= ~__shfl(r0w0, i); k1 &= ~__shfl(r0w1, i);
                        k2 &= ~__shfl(r0w2, i); k3 &= ~__shfl(r0w3, i);
                    }
            }
            if (V > 64) {
                int lim = (V - 64 < 64) ? V - 64 : 64;
                for (int i = 0; i < lim; ++i)
                    if ((k1 >> i) & 1) {
                        k1 &= ~__shfl(r1w1, i);
                        k2 &= ~__shfl(r1w2, i); k3 &= ~__shfl(r1w3, i);
                    }
            }
            if (V > 128) {
                int lim = (V - 128 < 64) ? V - 128 : 64;
                for (int i = 0; i < lim; ++i)
                    if ((k2 >> i) & 1) {
                        k2 &= ~__shfl(r2w2, i); k3 &= ~__shfl(r2w3, i);
                    }
            }
            if (V > 192) {
                int lim = V - 192;
                for (int i = 0; i < lim; ++i)
                    if ((k3 >> i) & 1) k3 &= ~__shfl(r3w3, i);
            }
            if (t == 0) { skw[0] = k0; skw[1] = k1; skw[2] = k2; skw[3] = k3; }
        }
        __syncthreads();
        if (t < V) {
            if ((skw[t >> 6] >> (t & 63)) & 1ull) {
                int pos = atomicAdd(counter, 1);
                u32 sb = (u32)(skey64[t] >> 32);
                ckey[pos] = ((u64)sb << 32) | (u64)(u32)~(u32)(c * N + t);
                atomicAdd(&hist[(int)(sb >> 16) - HBASE], 1);
            }
        }
    } else if (V > 256) {
        // ---------- safety fallback (not hit at these stats) ----------
        int P = 512;
        while (P < V) P <<= 1;
        for (int i = V + t; i < P; i += 256) skey64[i] = 0ull;
        __syncthreads();
        for (int k = 2; k <= P; k <<= 1) {
            for (int j = k >> 1; j > 0; j >>= 1) {
                for (int i = t; i < P; i += 256) {
                    int ixj = i ^ j;
                    if (ixj > i) {
                        u64 a = skey64[i], bb = skey64[ixj];
                        bool desc = ((i & k) == 0);
                        if (desc ? (a < bb) : (a > bb)) { skey64[i] = bb; skey64[ixj] = a; }
                    }
                }
                __syncthreads();
            }
        }
        for (int p = t; p < V; p += 256) {
            int idx = (int)(~(u32)(skey64[p] & 0xffffffffu));
            float4 b = decode_box(pboxes, boxreg, idx, cl);
            sbox[p]  = b;
            sarea[p] = (b.z - b.x + 1.0f) * (b.w - b.y + 1.0f);
            skeep[p] = 1;
            cbox[c * N + p]  = b;
            corig[c * N + p] = idx;
        }
        __syncthreads();
        for (int i = 0; i < V; ++i) {
            if (skeep[i]) {
                float4 bi = sbox[i];
                float  ai = sarea[i];
                for (int j = i + 1 + t; j < V; j += 256) {
                    if (skeep[j]) {
                        float4 bj = sbox[j];
                        float lx = fmaxf(bi.x, bj.x), ly = fmaxf(bi.y, bj.y);
                        float rx = fminf(bi.z, bj.z), ry = fminf(bi.w, bj.w);
                        float ww = fmaxf(rx - lx + 1.0f, 0.0f);
                        float hh = fmaxf(ry - ly + 1.0f, 0.0f);
                        float inter = ww * hh;
                        float iou = inter / (ai + sarea[j] - inter);
                        if (iou > NMS_THRESH) skeep[j] = 0;
                    }
                }
            }
            __syncthreads();
        }
        for (int p = t; p < V; p += 256) {
            if (skeep[p]) {
                int pos = atomicAdd(counter, 1);
                u32 sb = (u32)(skey64[p] >> 32);
                ckey[pos] = ((u64)sb << 32) | (u64)(u32)~(u32)(c * N + p);
                atomicAdd(&hist[(int)(sb >> 16) - HBASE], 1);
            }
        }
    }

    // ============ arrive: release writes, last block proceeds ==============
    __threadfence();                 // release: ckey/hist/cbox/corig visible
    __syncthreads();
    if (t == 0) sLast = (atomicAdd(done, 1) == NC1 - 1);
    __syncthreads();
    if (!sLast) return;
    __threadfence();                 // acquire: see all other blocks' writes

    // ============ select phase (last block, 256 threads) ===================
    {
        int M = *counter;
        if (t == 0) { sbstar = 0; scount = 0; }

        // suffix scan of 1024-bucket hist: thread t owns buckets 4t..4t+3.
        // wave-level shuffle suffix scan (round-7-proven construct); same
        // base/bstar arithmetic as the round-4/5-proven two-level version.
        int h0 = hist[4 * t], h1 = hist[4 * t + 1];
        int h2 = hist[4 * t + 2], h3 = hist[4 * t + 3];
        int gs = h0 + h1 + h2 + h3;
        int v = gs;
        #pragma unroll
        for (int off = 1; off < 64; off <<= 1) {
            int o = __shfl_down(v, off);
            if (lane + off < 64) v += o;
        }
        if (lane == 0) swsum4[wv] = v;
        __syncthreads();
        int higher = 0;
        for (int w = wv + 1; w < 4; ++w) higher += swsum4[w];
        int above = v + higher - gs;         // keys in bucket-groups above t
        int b3 = above, b2 = b3 + h3, b1 = b2 + h2, b0 = b1 + h1;
        if (b0 < K && b0 + h0 >= K) sbstar = 4 * t;
        if (b1 < K && b1 + h1 >= K) sbstar = 4 * t + 1;
        if (b2 < K && b2 + h2 >= K) sbstar = 4 * t + 2;
        if (b3 < K && b3 + h3 >= K) sbstar = 4 * t + 3;
        __syncthreads();
        int bstar = sbstar;

        // compact keys with bucket >= bstar into LDS (overlays sbox)
        u64* keys = (u64*)sbox;
        for (int p = t; p < M; p += 256) {
            u64 kk = ckey[p];
            int b = (int)((kk >> 48) & 0xFFFF) - HBASE;
            if (b >= bstar) {
                int pos = atomicAdd(&scount, 1);
                if (pos < SELCAP) keys[pos] = kk;
            }
        }
        __syncthreads();
        int cnt = scount;

        if (cnt > SELCAP) {
            // exact fallback (tie flood): K rounds of argmax over dense ckey
            for (int k = 0; k < K; ++k) {
                u64 key = 0ull; int pos = -1;
                for (int p = t; p < M; p += 256) {
                    u64 kk = ckey[p];
                    if (kk > key) { key = kk; pos = p; }
                }
                for (int off = 32; off; off >>= 1) {
                    u64 ok2 = __shfl_down(key, off);
                    int op  = __shfl_down(pos, off);
                    if (ok2 > key) { key = ok2; pos = op; }
                }
                if ((t & 63) == 0) { wk[t >> 6] = key; wp[t >> 6] = pos; }
                __syncthreads();
                if (t == 0) {
                    for (int w = 1; w < 4; ++w)
                        if (wk[w] > key) { key = wk[w]; pos = wp[w]; }
                    if (key != 0ull) {
                        ssel_score[k] = __uint_as_float((u32)(key >> 32));
                        ssel_flat[k]  = (int)(~(u32)(key & 0xffffffffu));
                        ckey[pos] = 0ull;
                    } else { ssel_score[k] = 0.0f; ssel_flat[k] = 0; }
                }
                __syncthreads();
            }
        } else {
            int P = 128;
            while (P < cnt) P <<= 1;
            for (int i = cnt + t; i < P; i += 256) keys[i] = 0ull;
            __syncthreads();
            if (P <= 256) {
                // register bitonic (round-7-proven): shuffles j<64, LDS j>=64
                u64 key = (t < P) ? keys[t] : 0ull;
                for (int k = 2; k <= P; k <<= 1) {
                    for (int j = k >> 1; j > 0; j >>= 1) {
                        if (j >= 64) {
                            if (t < P) keys[t] = key;
                            __syncthreads();
                            if (t < P) {
                                u64 other = keys[t ^ j];
                                bool takeMax = (((t & j) == 0) == ((t & k) == 0));
                                bool gt = key > other;
                                key = (takeMax == gt) ? key : other;
                            }
                            __syncthreads();
                        } else {
                            u64 other = __shfl_xor(key, j);
                            bool takeMax = (((t & j) == 0) == ((t & k) == 0));
                            bool gt = key > other;
                            if (t < P) key = (takeMax == gt) ? key : other;
                        }
                    }
                }
                if (t < K) {
                    ssel_score[t] = __uint_as_float((u32)(key >> 32));
                    ssel_flat[t]  = (int)(~(u32)(key & 0xffffffffu));
                }
            } else {
                // LDS bitonic (256 < cnt <= SELCAP), round-5-proven loop
                for (int k = 2; k <= P; k <<= 1) {
                    for (int j = k >> 1; j > 0; j >>= 1) {
                        for (int i = t; i < P; i += 256) {
                            int ixj = i ^ j;
                            if (ixj > i) {
                                u64 a = keys[i], b = keys[ixj];
                                bool desc = ((i & k) == 0);
                                if (desc ? (a < b) : (a > b)) { keys[i] = b; keys[ixj] = a; }
                            }
                        }
                        __syncthreads();
                    }
                }
                if (t < K) {
                    u64 key = keys[t];
                    ssel_score[t] = __uint_as_float((u32)(key >> 32));
                    ssel_flat[t]  = (int)(~(u32)(key & 0xffffffffu));
                }
            }
        }
    }
    __syncthreads();

    // ============ gather phase (same block) ================================
    // out layout: boxes[K*4] | scores[K] | feats[K*F] | labels[K]  (all f32)
    if (t < K) {
        float s = ssel_score[t];
        bool ok = s > 0.0f;
        float4 b = make_float4(0.f, 0.f, 0.f, 0.f);
        int label = 0, orig = 0;
        if (ok) {
            int flat = ssel_flat[t];       // c*N + rank
            orig  = corig[flat];
            b     = cbox[flat];
            label = (flat >> 10) + 1;      // N = 1024
        }
        sorig[t] = orig;
        sok[t]   = ok ? 1 : 0;
        out[t * 4 + 0] = b.x; out[t * 4 + 1] = b.y;
        out[t * 4 + 2] = b.z; out[t * 4 + 3] = b.w;
        out[K * 4 + t] = ok ? s : 0.0f;
        out[K * 4 + K + K * F + t] = (float)label;
    }
    __syncthreads();
    {
        float4 z = make_float4(0.f, 0.f, 0.f, 0.f);
        float4* dstbase = (float4*)(out + K * 4 + K);
        #pragma unroll 2
        for (int k = 0; k < K; ++k) {
            const float4* src = (const float4*)(feats + (size_t)sorig[k] * F);
            dstbase[(size_t)k * (F / 4) + t] = sok[k] ? src[t] : z;  // F/4==256
        }
    }
}

// ---------------------------------------------------------------------------
extern "C" void kernel_launch(void* const* d_in, const int* in_sizes, int n_in,
                              void* d_out, int out_size, void* d_ws, size_t ws_size,
                              hipStream_t stream)
{
    const float* logits = (const float*)d_in[0];   // [N,C]
    const float* boxreg = (const float*)d_in[1];   // [N,C*4]
    const float* pboxes = (const float*)d_in[2];   // [N,4]
    const float* feats  = (const float*)d_in[3];   // [N,F]
    float* out = (float*)d_out;

    char* ws = (char*)d_ws;
    size_t off = 0;
    auto alloc = [&](size_t bytes) {
        size_t cur = off;
        off = (off + bytes + 255) & ~(size_t)255;
        return cur;
    };
    u64*    ckey      = (u64*)   (ws + alloc(sizeof(u64)    * MAXC));
    float4* cbox      = (float4*)(ws + alloc(sizeof(float4) * NC1 * N));
    int*    corig     = (int*)   (ws + alloc(sizeof(int)    * NC1 * N));
    float2* ms        = (float2*)(ws + alloc(sizeof(float2) * N));
    int*    hist      = (int*)   (ws + alloc(sizeof(int)    * HSIZE));
    int*    counter   = (int*)   (ws + alloc(sizeof(int)));
    int*    done      = (int*)   (ws + alloc(sizeof(int)));

    hipLaunchKernelGGL(k_softmax, dim3(N / 4), dim3(256), 0, stream,
                       logits, ms, hist, counter, done);
    hipLaunchKernelGGL(k_mega, dim3(NC1), dim3(256), 0, stream,
                       logits, boxreg, pboxes, ms, feats,
                       ckey, cbox, corig, hist, counter, done, out);
}

// Round 9
// 95.054 us; speedup vs baseline: 1.1923x; 1.1923x over previous
//
#include <hip/hip_runtime.h>
#include <math.h>

#define N 1024
#define C 81
#define F 1024
#define K 100
#define NC1 80              // C-1 foreground classes
#define MAXC (NC1 * N)      // dense candidate capacity
#define HBASE 0x3D00        // hist bucket base: float bits >>16
#define HSIZE 1024          // covers score in (0.05, 1]: buckets 76..640
#define SELCAP 2048         // LDS select capacity

#define SCORE_THRESH 0.05f
#define NMS_THRESH   0.5f
#define BBOX_CLIP    4.135166556742356f   // log(1000/16)
#define IMG_W1       1215.0f
#define IMG_H1       799.0f

typedef unsigned long long u64;
typedef unsigned int u32;

// ---- decode one (proposal idx, class cl) box — expressions verbatim from the
// absmax==0 kernels so contraction/codegen matches.
__device__ float4 decode_box(const float* __restrict__ pboxes,
                             const float* __restrict__ boxreg, int idx, int cl)
{
    float4 pb = ((const float4*)pboxes)[idx];
    float4 r  = *(const float4*)(boxreg + (size_t)idx * (C * 4) + cl * 4);
    float w  = pb.z - pb.x + 1.0f, h = pb.w - pb.y + 1.0f;
    float cx = pb.x + 0.5f * w,  cy = pb.y + 0.5f * h;
    float dx = r.x / 10.0f, dy = r.y / 10.0f;
    float dw = fminf(r.z / 5.0f, BBOX_CLIP);
    float dh = fminf(r.w / 5.0f, BBOX_CLIP);
    float pcx = dx * w + cx, pcy = dy * h + cy;
    float pw = expf(dw) * w, ph = expf(dh) * h;
    float x1 = pcx - 0.5f * pw,        y1 = pcy - 0.5f * ph;
    float x2 = pcx + 0.5f * pw - 1.0f, y2 = pcy + 0.5f * ph - 1.0f;
    x1 = fminf(fmaxf(x1, 0.0f), IMG_W1);
    y1 = fminf(fmaxf(y1, 0.0f), IMG_H1);
    x2 = fminf(fmaxf(x2, 0.0f), IMG_W1);
    y2 = fminf(fmaxf(y2, 0.0f), IMG_H1);
    return make_float4(x1, y1, x2, y2);
}

// ---------------- per-row softmax stats (m, s), computed ONCE ---------------
// one wave per row, bit-exact replica of the original butterfly. Also zeroes
// hist + counter (grid covers HSIZE threads). ms[r] = (max, denom).
__global__ __launch_bounds__(256) void k_softmax(
    const float* __restrict__ logits, float2* __restrict__ ms,
    int* __restrict__ hist, int* __restrict__ counter)
{
    int gid = blockIdx.x * 256 + threadIdx.x;
    if (gid < HSIZE) hist[gid] = 0;
    if (gid == 0) *counter = 0;

    int n = blockIdx.x * 4 + (threadIdx.x >> 6);
    int t = threadIdx.x & 63;

    float v1 = logits[n * C + t];
    float v2 = (t < C - 64) ? logits[n * C + 64 + t] : -INFINITY;
    float m = fmaxf(v1, v2);
    for (int off = 32; off; off >>= 1) m = fmaxf(m, __shfl_xor(m, off));
    float e1 = expf(v1 - m);
    float e2 = (t < C - 64) ? expf(v2 - m) : 0.0f;
    float s = e1 + e2;
    for (int off = 32; off; off >>= 1) s += __shfl_xor(s, off);

    if (t == 0) ms[n] = make_float2(m, s);
}

// ---------------- per-class: score -> threshold -> sort -> NMS --------------
// one block per foreground class (byte-identical to round 7's proven k_class).
__global__ __launch_bounds__(256) void k_class(
    const float* __restrict__ logits, const float* __restrict__ boxreg,
    const float* __restrict__ pboxes, const float2* __restrict__ ms,
    u64* __restrict__ ckey, float4* __restrict__ cbox, int* __restrict__ corig,
    int* __restrict__ hist, int* __restrict__ counter)
{
    int c = blockIdx.x;            // foreground class (label = c+1)
    int cl = c + 1;
    int t = threadIdx.x;
    int lane = t & 63, wv = t >> 6;

    __shared__ u64    skey64[N];
    __shared__ float4 sbox[N];
    __shared__ float  sarea[N];
    __shared__ int    skeep[N];
    __shared__ u64    sup[256][4];     // suppression matrix for V<=256
    __shared__ u64    skw[4];          // final keep words
    __shared__ int    swc[4];          // per-wave candidate counts

    // ---- scores (identical bits to old probsT entries) ----
    float2 p0 = ms[t],       p1 = ms[t + 256];
    float2 p2 = ms[t + 512], p3 = ms[t + 768];
    float s0 = expf(logits[(t      ) * C + cl] - p0.x) / p0.y;
    float s1 = expf(logits[(t + 256) * C + cl] - p1.x) / p1.y;
    float s2 = expf(logits[(t + 512) * C + cl] - p2.x) / p2.y;
    float s3 = expf(logits[(t + 768) * C + cl] - p3.x) / p3.y;
    int f0 = s0 > SCORE_THRESH, f1 = s1 > SCORE_THRESH;
    int f2 = s2 > SCORE_THRESH, f3 = s3 > SCORE_THRESH;

    // ---- ballot compaction (2 barriers instead of 16) ----
    u64 lmask = (1ull << lane) - 1ull;
    u64 b0 = __ballot(f0), b1 = __ballot(f1);
    u64 b2 = __ballot(f2), b3 = __ballot(f3);
    int wcount = __popcll(b0) + __popcll(b1) + __popcll(b2) + __popcll(b3);
    if (lane == 0) swc[wv] = wcount;
    __syncthreads();
    int w0c = swc[0], w1c = swc[1], w2c = swc[2], w3c = swc[3];
    int V = w0c + w1c + w2c + w3c;
    int wbase = (wv > 0 ? w0c : 0) + (wv > 1 ? w1c : 0) + (wv > 2 ? w2c : 0);
    {
        int o0 = wbase;
        int o1 = o0 + __popcll(b0);
        int o2 = o1 + __popcll(b1);
        int o3 = o2 + __popcll(b2);
        if (f0) skey64[o0 + __popcll(b0 & lmask)] =
            ((u64)__float_as_uint(s0) << 32) | (u32)~(u32)(t);
        if (f1) skey64[o1 + __popcll(b1 & lmask)] =
            ((u64)__float_as_uint(s1) << 32) | (u32)~(u32)(t + 256);
        if (f2) skey64[o2 + __popcll(b2 & lmask)] =
            ((u64)__float_as_uint(s2) << 32) | (u32)~(u32)(t + 512);
        if (f3) skey64[o3 + __popcll(b3 & lmask)] =
            ((u64)__float_as_uint(s3) << 32) | (u32)~(u32)(t + 768);
    }
    __syncthreads();
    if (V == 0) return;

    if (V <= 64) {
        // ---------- proven wave path ----------
        if (t < 64) {
            u64 key = (lane < V) ? skey64[lane] : 0ull;
            // descending bitonic over 64 lanes (keys unique; 0-pad sinks)
            for (int k = 2; k <= 64; k <<= 1) {
                for (int j = k >> 1; j > 0; j >>= 1) {
                    u64 other = __shfl_xor(key, j);
                    bool takeMax = (((lane & j) == 0) == ((lane & k) == 0));
                    bool gt = key > other;
                    key = (takeMax == gt) ? key : other;
                }
            }
            bool act = key != 0ull;
            float4 b = make_float4(0.f, 0.f, 0.f, 0.f);
            float area = 0.0f;
            if (act) {
                int idx = (int)(~(u32)(key & 0xffffffffu));
                b = decode_box(pboxes, boxreg, idx, cl);
                area = (b.z - b.x + 1.0f) * (b.w - b.y + 1.0f);
                cbox[c * N + lane]  = b;
                corig[c * N + lane] = idx;
            }
            int kept = act ? 1 : 0;
            for (int i = 0; i + 1 < V; ++i) {
                int   ki  = __shfl(kept, i);
                float bix = __shfl(b.x, i), biy = __shfl(b.y, i);
                float biz = __shfl(b.z, i), biw = __shfl(b.w, i);
                float ai  = __shfl(area, i);
                if (ki && lane > i && kept) {
                    float lx = fmaxf(bix, b.x), ly = fmaxf(biy, b.y);
                    float rx = fminf(biz, b.z), ry = fminf(biw, b.w);
                    float ww = fmaxf(rx - lx + 1.0f, 0.0f);
                    float hh = fmaxf(ry - ly + 1.0f, 0.0f);
                    float inter = ww * hh;
                    float iou = inter / (ai + area - inter);
                    if (iou > NMS_THRESH) kept = 0;
                }
            }
            if (kept) {
                int pos = atomicAdd(counter, 1);
                u32 sb = (u32)(key >> 32);
                ckey[pos] = ((u64)sb << 32) | (u64)(u32)~(u32)(c * N + lane);
                atomicAdd(&hist[(int)(sb >> 16) - HBASE], 1);
            }
        }
        return;
    }

    if (V <= 256) {
        // ---------- LDS bitonic sort on P = next pow2 (<=256) ----------
        int P = 128;
        while (P < V) P <<= 1;
        for (int i = V + t; i < P; i += 256) skey64[i] = 0ull;
        __syncthreads();
        for (int k = 2; k <= P; k <<= 1) {
            for (int j = k >> 1; j > 0; j >>= 1) {
                if (t < P) {
                    int i = t, ixj = i ^ j;
                    if (ixj > i) {
                        u64 a = skey64[i], bb = skey64[ixj];
                        bool desc = ((i & k) == 0);
                        if (desc ? (a < bb) : (a > bb)) { skey64[i] = bb; skey64[ixj] = a; }
                    }
                }
                __syncthreads();
            }
        }
        // decode sorted candidates
        for (int p = t; p < V; p += 256) {
            int idx = (int)(~(u32)(skey64[p] & 0xffffffffu));
            float4 b = decode_box(pboxes, boxreg, idx, cl);
            sbox[p]  = b;
            sarea[p] = (b.z - b.x + 1.0f) * (b.w - b.y + 1.0f);
            cbox[c * N + p]  = b;
            corig[c * N + p] = idx;
        }
        __syncthreads();
        // parallel suppression matrix: row i, bit j (j>i): iou(i,j) > T
        for (int i = t; i < V; i += 256) {
            float4 bi = sbox[i];
            float  ai = sarea[i];
            u64 w[4] = {0ull, 0ull, 0ull, 0ull};
            #pragma unroll
            for (int g = 0; g < 4; ++g) {
                int jlo = (i + 1 > g * 64) ? i + 1 : g * 64;
                int jhi = (V < (g + 1) * 64) ? V : (g + 1) * 64;
                for (int j = jlo; j < jhi; ++j) {
                    float4 bj = sbox[j];
                    float lx = fmaxf(bi.x, bj.x), ly = fmaxf(bi.y, bj.y);
                    float rx = fminf(bi.z, bj.z), ry = fminf(bi.w, bj.w);
                    float ww = fmaxf(rx - lx + 1.0f, 0.0f);
                    float hh = fmaxf(ry - ly + 1.0f, 0.0f);
                    float inter = ww * hh;
                    float iou = inter / (ai + sarea[j] - inter);
                    if (iou > NMS_THRESH) w[g] |= 1ull << (j & 63);
                }
            }
            sup[i][0] = w[0]; sup[i][1] = w[1];
            sup[i][2] = w[2]; sup[i][3] = w[3];
        }
        __syncthreads();
        // barrier-free walk on wave 0: rows register-resident, rows via shfl.
        // Semantics identical to: for i asc: if keep[i]: keep &= ~sup[i].
        if (t < 64) {
            u64 r0w0 = sup[t][0], r0w1 = sup[t][1], r0w2 = sup[t][2], r0w3 = sup[t][3];
            u64 r1w1 = 0, r1w2 = 0, r1w3 = 0;
            u64 r2w2 = 0, r2w3 = 0;
            u64 r3w3 = 0;
            if (64 + t < V)  { r1w1 = sup[64 + t][1];  r1w2 = sup[64 + t][2];  r1w3 = sup[64 + t][3]; }
            if (128 + t < V) { r2w2 = sup[128 + t][2]; r2w3 = sup[128 + t][3]; }
            if (192 + t < V) { r3w3 = sup[192 + t][3]; }
            u64 k0 = ~0ull, k1 = ~0ull, k2 = ~0ull, k3 = ~0ull;
            {
                int lim = (V < 64) ? V : 64;
                for (int i = 0; i < lim; ++i)
                    if ((k0 >> i) & 1) {
                        k0 &= ~__shfl(r0w0, i); k1 &= ~__shfl(r0w1, i);
                        k2 &= ~__shfl(r0w2, i); k3 &= ~__shfl(r0w3, i);
                    }
            }
            if (V > 64) {
                int lim = (V - 64 < 64) ? V - 64 : 64;
                for (int i = 0; i < lim; ++i)
                    if ((k1 >> i) & 1) {
                        k1 &= ~__shfl(r1w1, i);
                        k2 &= ~__shfl(r1w2, i); k3 &= ~__shfl(r1w3, i);
                    }
            }
            if (V > 128) {
                int lim = (V - 128 < 64) ? V - 128 : 64;
                for (int i = 0; i < lim; ++i)
                    if ((k2 >> i) & 1) {
                        k2 &= ~__shfl(r2w2, i); k3 &= ~__shfl(r2w3, i);
                    }
            }
            if (V > 192) {
                int lim = V - 192;
                for (int i = 0; i < lim; ++i)
                    if ((k3 >> i) & 1) k3 &= ~__shfl(r3w3, i);
            }
            if (t == 0) { skw[0] = k0; skw[1] = k1; skw[2] = k2; skw[3] = k3; }
        }
        __syncthreads();
        for (int p = t; p < V; p += 256) {
            if ((skw[p >> 6] >> (p & 63)) & 1ull) {
                int pos = atomicAdd(counter, 1);
                u32 sb = (u32)(skey64[p] >> 32);
                ckey[pos] = ((u64)sb << 32) | (u64)(u32)~(u32)(c * N + p);
                atomicAdd(&hist[(int)(sb >> 16) - HBASE], 1);
            }
        }
        return;
    }

    // ---------- safety fallback: V > 256 (not hit at these stats) ----------
    {
        int P = 512;
        while (P < V) P <<= 1;
        for (int i = V + t; i < P; i += 256) skey64[i] = 0ull;
        __syncthreads();
        for (int k = 2; k <= P; k <<= 1) {
            for (int j = k >> 1; j > 0; j >>= 1) {
                for (int i = t; i < P; i += 256) {
                    int ixj = i ^ j;
                    if (ixj > i) {
                        u64 a = skey64[i], bb = skey64[ixj];
                        bool desc = ((i & k) == 0);
                        if (desc ? (a < bb) : (a > bb)) { skey64[i] = bb; skey64[ixj] = a; }
                    }
                }
                __syncthreads();
            }
        }
        for (int p = t; p < V; p += 256) {
            int idx = (int)(~(u32)(skey64[p] & 0xffffffffu));
            float4 b = decode_box(pboxes, boxreg, idx, cl);
            sbox[p]  = b;
            sarea[p] = (b.z - b.x + 1.0f) * (b.w - b.y + 1.0f);
            skeep[p] = 1;
            cbox[c * N + p]  = b;
            corig[c * N + p] = idx;
        }
        __syncthreads();
        for (int i = 0; i < V; ++i) {
            if (skeep[i]) {
                float4 bi = sbox[i];
                float  ai = sarea[i];
                for (int j = i + 1 + t; j < V; j += 256) {
                    if (skeep[j]) {
                        float4 bj = sbox[j];
                        float lx = fmaxf(bi.x, bj.x), ly = fmaxf(bi.y, bj.y);
                        float rx = fminf(bi.z, bj.z), ry = fminf(bi.w, bj.w);
                        float ww = fmaxf(rx - lx + 1.0f, 0.0f);
                        float hh = fmaxf(ry - ly + 1.0f, 0.0f);
                        float inter = ww * hh;
                        float iou = inter / (ai + sarea[j] - inter);
                        if (iou > NMS_THRESH) skeep[j] = 0;
                    }
                }
            }
            __syncthreads();
        }
        for (int p = t; p < V; p += 256) {
            if (skeep[p]) {
                int pos = atomicAdd(counter, 1);
                u32 sb = (u32)(skey64[p] >> 32);
                ckey[pos] = ((u64)sb << 32) | (u64)(u32)~(u32)(c * N + p);
                atomicAdd(&hist[(int)(sb >> 16) - HBASE], 1);
            }
        }
    }
}

// ---------------- exact top-K + box/score/label emission -------------------
// Round-7 proven select (wave suffix scan + register bitonic), plus the
// round-8-proven epilogue: this block already holds the top-K, so it writes
// boxes/scores/labels directly and publishes sorig_ok for the feature gather.
__global__ __launch_bounds__(1024) void k_select(
    const int* __restrict__ counter, u64* ckey, const int* __restrict__ hist,
    const int* __restrict__ corig, const float4* __restrict__ cbox,
    int* __restrict__ sorig_ok, float* __restrict__ out)
{
    int t = threadIdx.x;
    int lane = t & 63, wv = t >> 6;
    __shared__ u64 keys[SELCAP];
    __shared__ int swsum[16];
    __shared__ int sb_bstar, scount;
    __shared__ u64 wk[16];
    __shared__ int wp[16];
    __shared__ float ssel_score[K];
    __shared__ int   ssel_flat[K];

    int M = *counter;
    if (t == 0) { sb_bstar = 0; scount = 0; }

    // phase 1: suffix scan of 1024-bucket histogram -> bucket of K-th key
    int lsum = hist[t];
    int v = lsum;
    #pragma unroll
    for (int off = 1; off < 64; off <<= 1) {
        int o = __shfl_down(v, off);
        if (lane + off < 64) v += o;
    }
    if (lane == 0) swsum[wv] = v;          // per-wave total
    __syncthreads();
    if (t < 64) {
        int w = (t < 16) ? swsum[t] : 0;
        #pragma unroll
        for (int off = 1; off < 16; off <<= 1) {
            int o = __shfl_down(w, off);
            if (t + off < 16) w += o;
        }
        if (t < 16) swsum[t] = w;          // suffix-inclusive wave totals
    }
    __syncthreads();
    int higher = (wv < 15) ? swsum[wv + 1] : 0;
    int base = v + higher - lsum;          // keys in buckets above t
    if (base < K && base + lsum >= K) sb_bstar = t;
    __syncthreads();
    int bstar = sb_bstar;

    // phase 2: compact keys with bucket >= bstar
    for (int p = t; p < M; p += 1024) {
        u64 kk = ckey[p];
        int b = (int)((kk >> 48) & 0xFFFF) - HBASE;
        if (b >= bstar) {
            int pos = atomicAdd(&scount, 1);
            if (pos < SELCAP) keys[pos] = kk;
        }
    }
    __syncthreads();
    int cnt = scount;

    if (cnt > SELCAP) {
        // exact fallback (tie flood): K rounds of argmax over dense ckey
        for (int k = 0; k < K; ++k) {
            u64 key = 0ull; int pos = -1;
            for (int p = t; p < M; p += 1024) {
                u64 kk = ckey[p];
                if (kk > key) { key = kk; pos = p; }
            }
            for (int off = 32; off; off >>= 1) {
                u64 ok2 = __shfl_down(key, off);
                int op = __shfl_down(pos, off);
                if (ok2 > key) { key = ok2; pos = op; }
            }
            if ((t & 63) == 0) { wk[t >> 6] = key; wp[t >> 6] = pos; }
            __syncthreads();
            if (t == 0) {
                for (int w = 1; w < 16; ++w)
                    if (wk[w] > key) { key = wk[w]; pos = wp[w]; }
                if (key != 0ull) {
                    ssel_score[k] = __uint_as_float((u32)(key >> 32));
                    ssel_flat[k]  = (int)(~(u32)(key & 0xffffffffu));
                    ckey[pos] = 0ull;
                } else { ssel_score[k] = 0.0f; ssel_flat[k] = 0; }
            }
            __syncthreads();
        }
    } else {
        // phase 3: bitonic sort padded selection
        int P = 128;
        while (P < cnt) P <<= 1;
        for (int i = cnt + t; i < P; i += 1024) keys[i] = 0ull;
        __syncthreads();

        if (P <= 1024) {
            // register bitonic: shuffles for j<64, LDS round-trip for j>=64
            u64 key = (t < P) ? keys[t] : 0ull;
            for (int k = 2; k <= P; k <<= 1) {
                for (int j = k >> 1; j > 0; j >>= 1) {
                    if (j >= 64) {
                        if (t < P) keys[t] = key;
                        __syncthreads();
                        if (t < P) {
                            u64 other = keys[t ^ j];
                            bool takeMax = (((t & j) == 0) == ((t & k) == 0));
                            bool gt = key > other;
                            key = (takeMax == gt) ? key : other;
                        }
                        __syncthreads();
                    } else {
                        u64 other = __shfl_xor(key, j);
                        bool takeMax = (((t & j) == 0) == ((t & k) == 0));
                        bool gt = key > other;
                        if (t < P) key = (takeMax == gt) ? key : other;
                    }
                }
            }
            if (t < K) {
                ssel_score[t] = __uint_as_float((u32)(key >> 32));
                ssel_flat[t]  = (int)(~(u32)(key & 0xffffffffu));
            }
        } else {
            // LDS bitonic fallback (P > 1024; cnt in (1024, 2048])
            for (int k = 2; k <= P; k <<= 1) {
                for (int j = k >> 1; j > 0; j >>= 1) {
                    for (int i = t; i < P; i += 1024) {
                        int ixj = i ^ j;
                        if (ixj > i) {
                            u64 a = keys[i], b = keys[ixj];
                            bool desc = ((i & k) == 0);
                            if (desc ? (a < b) : (a > b)) { keys[i] = b; keys[ixj] = a; }
                        }
                    }
                    __syncthreads();
                }
            }
            if (t < K) {
                u64 key = keys[t];
                ssel_score[t] = __uint_as_float((u32)(key >> 32));
                ssel_flat[t]  = (int)(~(u32)(key & 0xffffffffu));
            }
        }
    }
    __syncthreads();

    // epilogue (round-8-proven gather head): boxes/scores/labels + sorig_ok.
    // out layout: boxes[K*4] | scores[K] | feats[K*F] | labels[K]  (all f32)
    if (t < K) {
        float s = ssel_score[t];
        bool ok = s > 0.0f;
        float4 b = make_float4(0.f, 0.f, 0.f, 0.f);
        int label = 0, orig = 0;
        if (ok) {
            int flat = ssel_flat[t];       // c*N + rank
            orig  = corig[flat];
            b     = cbox[flat];
            label = (flat >> 10) + 1;      // N = 1024
        }
        out[t * 4 + 0] = b.x; out[t * 4 + 1] = b.y;
        out[t * 4 + 2] = b.z; out[t * 4 + 3] = b.w;
        out[K * 4 + t] = ok ? s : 0.0f;
        out[K * 4 + K + K * F + t] = (float)label;
        sorig_ok[t] = ok ? (orig + 1) : 0;
    }
}

// ---------------- gather: pure feature-row copy ----------------------------
__global__ __launch_bounds__(256) void k_gather(
    const int* __restrict__ sorig_ok, const float* __restrict__ feats,
    float* __restrict__ out)
{
    int k = blockIdx.x, t = threadIdx.x;
    int v = sorig_ok[k];
    bool ok = v > 0;
    int orig = ok ? (v - 1) : 0;
    const float4* src = (const float4*)(feats + (size_t)orig * F);
    float4* dst = (float4*)(out + K * 4 + K + (size_t)k * F);
    float4 z = make_float4(0.f, 0.f, 0.f, 0.f);
    dst[t] = ok ? src[t] : z;              // F/4 == 256 == blockDim
}

// ---------------------------------------------------------------------------
extern "C" void kernel_launch(void* const* d_in, const int* in_sizes, int n_in,
                              void* d_out, int out_size, void* d_ws, size_t ws_size,
                              hipStream_t stream)
{
    const float* logits = (const float*)d_in[0];   // [N,C]
    const float* boxreg = (const float*)d_in[1];   // [N,C*4]
    const float* pboxes = (const float*)d_in[2];   // [N,4]
    const float* feats  = (const float*)d_in[3];   // [N,F]
    float* out = (float*)d_out;

    char* ws = (char*)d_ws;
    size_t off = 0;
    auto alloc = [&](size_t bytes) {
        size_t cur = off;
        off = (off + bytes + 255) & ~(size_t)255;
        return cur;
    };
    u64*    ckey      = (u64*)   (ws + alloc(sizeof(u64)    * MAXC));
    float4* cbox      = (float4*)(ws + alloc(sizeof(float4) * NC1 * N));
    int*    corig     = (int*)   (ws + alloc(sizeof(int)    * NC1 * N));
    float2* ms        = (float2*)(ws + alloc(sizeof(float2) * N));
    int*    hist      = (int*)   (ws + alloc(sizeof(int)    * HSIZE));
    int*    counter   = (int*)   (ws + alloc(sizeof(int)));
    int*    sorig_ok  = (int*)   (ws + alloc(sizeof(int)    * K));

    hipLaunchKernelGGL(k_softmax, dim3(N / 4), dim3(256), 0, stream,
                       logits, ms, hist, counter);
    hipLaunchKernelGGL(k_class, dim3(NC1), dim3(256), 0, stream,
                       logits, boxreg, pboxes, ms, ckey, cbox, corig, hist, counter);
    hipLaunchKernelGGL(k_select, dim3(1), dim3(1024), 0, stream,
                       counter, ckey, hist, corig, cbox, sorig_ok, out);
    hipLaunchKernelGGL(k_gather, dim3(K), dim3(256), 0, stream,
                       sorig_ok, feats, out);
}